// Round 9
// baseline (752.939 us; speedup 1.0000x reference)
//
#include <hip/hip_runtime.h>
#include <hip/hip_bf16.h>
#include <stdint.h>

typedef float floatx2 __attribute__((ext_vector_type(2)));

#define NPB 512          // nodes per bucket (node>>9)
#define NB 196           // ceil(100000/512)
#define NBLKA 128        // blocks in passes A1/A2 (must match)

__device__ __forceinline__ float rdlane(float v, int l) {
    return __uint_as_float(__builtin_amdgcn_readlane(__float_as_uint(v), l));
}
// pack 4 floats -> 4 fp8 e4m3 (HW cvt, RNE)
__device__ __forceinline__ unsigned pk_fp8x4(float a, float b, float c, float d) {
    int u = __builtin_amdgcn_cvt_pk_fp8_f32(a, b, 0, false);
    u = __builtin_amdgcn_cvt_pk_fp8_f32(c, d, u, true);
    return (unsigned)u;
}
__device__ __forceinline__ unsigned pk_fp8x2(float a, float b) {
    return (unsigned)__builtin_amdgcn_cvt_pk_fp8_f32(a, b, 0, false);
}

// ---------------- zero inTot + pooled sums ----------------------------------
__global__ __launch_bounds__(512) void k_zero(int* __restrict__ inTot,
                                              double* __restrict__ sums) {
    int t = threadIdx.x;
    if (t < 128) sums[t] = 0.0;
    if (t < NB) inTot[t] = 0;
}

// ------- A1: bucket histograms (LDS) + edge MLP -> streaming efp ------------
// MLP VALU rides free under the LDS-atomic + streaming traffic (R5 lesson).
__global__ __launch_bounds__(256) void k_A1(
    const int* __restrict__ ei, const float* __restrict__ ea,
    const float* __restrict__ We1, const float* __restrict__ be1,
    const float* __restrict__ We2, const float* __restrict__ be2,
    uint2* __restrict__ efp, int* __restrict__ h, int* __restrict__ inTot,
    int E, int epb) {
    __shared__ float sWe1[128], sbe1[64], sWe2[64 * 6], sbe2[6];
    __shared__ int hist[NB], histIn[NB];
    int t = threadIdx.x, blk = blockIdx.x;
    if (t < 128) sWe1[t] = We1[t];
    if (t < 64) {
        sbe1[t] = be1[t];
#pragma unroll
        for (int c = 0; c < 6; ++c) sWe2[t * 6 + c] = We2[t * 64 + c];
    }
    if (t < 6) sbe2[t] = be2[t];
    for (int b = t; b < NB; b += 256) { hist[b] = 0; histIn[b] = 0; }
    __syncthreads();

    int e0 = blk * epb, e1 = min(E, e0 + epb);
    for (int e = e0 + t; e < e1; e += 256) {
        int s = ei[e], d = ei[E + e];
        atomicAdd(&hist[s >> 9], 1);
        atomicAdd(&hist[d >> 9], 1);
        atomicAdd(&histIn[d >> 9], 1);
        float2 aa = ((const float2*)ea)[e];
        float acc[6];
#pragma unroll
        for (int c = 0; c < 6; ++c) acc[c] = sbe2[c];
#pragma unroll
        for (int j = 0; j < 64; ++j) {
            float hh = fmaf(aa.x, sWe1[j], fmaf(aa.y, sWe1[64 + j], sbe1[j]));
            hh = fmaxf(hh, 0.f);
#pragma unroll
            for (int c = 0; c < 6; ++c) acc[c] = fmaf(hh, sWe2[j * 6 + c], acc[c]);
        }
        efp[e] = make_uint2(pk_fp8x4(acc[0], acc[1], acc[2], acc[3]),
                            pk_fp8x2(acc[4], acc[5]));
    }
    __syncthreads();
    for (int b = t; b < NB; b += 256) {
        h[(size_t)b * NBLKA + blk] = hist[b];
        if (histIn[b]) atomicAdd(&inTot[b], histIn[b]);
    }
}

// ---------------- int scans (512-thread, 3-pass, in-place) ------------------
__global__ __launch_bounds__(512) void k_sc1(const int* __restrict__ v,
                                             int* __restrict__ bsum, int n) {
    __shared__ int l[512];
    int i = blockIdx.x * 512 + threadIdx.x;
    l[threadIdx.x] = (i < n) ? v[i] : 0;
    __syncthreads();
    for (int s = 256; s > 0; s >>= 1) {
        if (threadIdx.x < s) l[threadIdx.x] += l[threadIdx.x + s];
        __syncthreads();
    }
    if (threadIdx.x == 0) bsum[blockIdx.x] = l[0];
}
__global__ __launch_bounds__(512) void k_sc2(int* __restrict__ bsum, int nb) {
    __shared__ int l[512];
    int t = threadIdx.x;
    int v = (t < nb) ? bsum[t] : 0;
    l[t] = v;
    __syncthreads();
    for (int s = 1; s < 512; s <<= 1) {
        int tmp = (t >= s) ? l[t - s] : 0;
        __syncthreads();
        l[t] += tmp;
        __syncthreads();
    }
    if (t < nb) bsum[t] = l[t] - v;  // exclusive
}
__global__ __launch_bounds__(512) void k_sc3(int* __restrict__ v,
                                             const int* __restrict__ bsum, int n) {
    __shared__ int l[512];
    int i = blockIdx.x * 512 + threadIdx.x;
    int x = (i < n) ? v[i] : 0;
    l[threadIdx.x] = x;
    __syncthreads();
    for (int s = 1; s < 512; s <<= 1) {
        int tmp = (threadIdx.x >= (unsigned)s) ? l[threadIdx.x - s] : 0;
        __syncthreads();
        l[threadIdx.x] += tmp;
        __syncthreads();
    }
    if (i < n) v[i] = l[threadIdx.x] - x + bsum[blockIdx.x];
}
__global__ __launch_bounds__(512) void k_scanIn(const int* __restrict__ inTot,
                                                int* __restrict__ inBase) {
    __shared__ int l[512];
    int t = threadIdx.x;
    int v = (t < NB) ? inTot[t] : 0;
    l[t] = v;
    __syncthreads();
    for (int s = 1; s < 512; s <<= 1) {
        int tmp = (t >= s) ? l[t - s] : 0;
        __syncthreads();
        l[t] += tmp;
        __syncthreads();
    }
    if (t < NB) inBase[t] = l[t] - v;
}

// ------- A2: pure bucketed record scatter (low VGPR, LDS cursors) -----------
// record uint4: x=(node<<1)|isIn  y=src(in only)  z,w = ef fp8x6
__global__ __launch_bounds__(256) void k_A2(const int* __restrict__ ei,
                                            const uint2* __restrict__ efp,
                                            const int* __restrict__ hs,
                                            uint4* __restrict__ rec, int E, int epb) {
    __shared__ int cur[NB];
    int t = threadIdx.x, blk = blockIdx.x;
    for (int b = t; b < NB; b += 256) cur[b] = hs[(size_t)b * NBLKA + blk];
    __syncthreads();
    int e0 = blk * epb, e1 = min(E, e0 + epb);
    for (int e = e0 + t; e < e1; e += 256) {
        int s = ei[e], d = ei[E + e];
        uint2 f = efp[e];
        int p0 = atomicAdd(&cur[s >> 9], 1);
        rec[p0] = make_uint4((unsigned)(s << 1), 0u, f.x, f.y);
        int p1 = atomicAdd(&cur[d >> 9], 1);
        rec[p1] = make_uint4((unsigned)(d << 1) | 1u, (unsigned)s, f.x, f.y);
    }
}

// ------- B: per-bucket (512 nodes): nef/deg/indeg -> xp, dinv, offI, in_src -
__global__ __launch_bounds__(512) void k_B(
    const uint4* __restrict__ rec, const int* __restrict__ hs,
    const int* __restrict__ inBase, const float* __restrict__ x,
    float* __restrict__ xp, float* __restrict__ dinv,
    int* __restrict__ offI, int* __restrict__ in_src, int E, int N) {
    __shared__ float nef[NPB * 6];
    __shared__ int degAll[NPB], degIn[NPB], rnk[NPB], sc[NPB], exO[NPB];
    int t = threadIdx.x, b = blockIdx.x;
#pragma unroll
    for (int c = 0; c < 6; ++c) nef[t * 6 + c] = 0.f;
    degAll[t] = 0; degIn[t] = 0; rnk[t] = 0;
    __syncthreads();

    int rb = hs[(size_t)b * NBLKA];
    int re = (b == NB - 1) ? 2 * E : hs[(size_t)(b + 1) * NBLKA];
    for (int j = rb + t; j < re; j += 512) {
        uint4 r = rec[j];
        int l = (int)((r.x >> 1) & (NPB - 1));
        atomicAdd(&degAll[l], 1);
        if (r.x & 1u) atomicAdd(&degIn[l], 1);
        floatx2 p01 = __builtin_amdgcn_cvt_pk_f32_fp8(r.z, false);
        floatx2 p23 = __builtin_amdgcn_cvt_pk_f32_fp8(r.z, true);
        floatx2 p45 = __builtin_amdgcn_cvt_pk_f32_fp8(r.w, false);
        atomicAdd(&nef[l * 6 + 0], p01.x);
        atomicAdd(&nef[l * 6 + 1], p01.y);
        atomicAdd(&nef[l * 6 + 2], p23.x);
        atomicAdd(&nef[l * 6 + 3], p23.y);
        atomicAdd(&nef[l * 6 + 4], p45.x);
        atomicAdd(&nef[l * 6 + 5], p45.y);
    }
    __syncthreads();

    // exclusive LDS scan of degIn over 512
    int v = degIn[t];
    sc[t] = v;
    __syncthreads();
    for (int s = 1; s < 512; s <<= 1) {
        int tmp = (t >= s) ? sc[t - s] : 0;
        __syncthreads();
        sc[t] += tmp;
        __syncthreads();
    }
    exO[t] = sc[t] - v;
    __syncthreads();

    int node = b * NPB + t;
    int ib = inBase[b];
    if (node <= N) offI[node] = ib + exO[t];  // node==N -> offI[N]=E
    if (node < N) {
        float da = (float)degAll[t];
        float inv = 0.5f / fmaxf(da, 1.f);
        const float2* xr = (const float2*)(x + (size_t)node * 6);
        float2 x01 = xr[0], x23 = xr[1], x45 = xr[2];
        float2* xw = (float2*)(xp + (size_t)node * 6);
        xw[0] = make_float2(x01.x + nef[t * 6 + 0] * inv, x01.y + nef[t * 6 + 1] * inv);
        xw[1] = make_float2(x23.x + nef[t * 6 + 2] * inv, x23.y + nef[t * 6 + 3] * inv);
        xw[2] = make_float2(x45.x + nef[t * 6 + 4] * inv, x45.y + nef[t * 6 + 5] * inv);
        dinv[node] = 1.f / sqrtf(1.f + (float)degIn[t]);
    }
    __syncthreads();

    // sweep 2: in-CSR build (writes confined to bucket's ~32KB L2 region)
    for (int j = rb + t; j < re; j += 512) {
        uint4 r = rec[j];
        if (r.x & 1u) {
            int l = (int)((r.x >> 1) & (NPB - 1));
            int k = atomicAdd(&rnk[l], 1);
            in_src[ib + exO[l] + k] = (int)r.y;
        }
    }
}

// ------- layer 1: s1 = fp8(dinv * (x'(N,6) @ W1)), rows = 16 uints ----------
__global__ __launch_bounds__(256) void k_mm1(const float* __restrict__ xp,
                                             const float* __restrict__ W1,
                                             const float* __restrict__ dinv,
                                             unsigned* __restrict__ sOut, int n) {
    int lane = threadIdx.x & 63;
    int sub = lane & 15;
    int wid = (blockIdx.x * blockDim.x + threadIdx.x) >> 6;
    int nw = (gridDim.x * blockDim.x) >> 6;
    float w[6];
#pragma unroll
    for (int c = 0; c < 6; ++c) w[c] = W1[c * 64 + lane];
    for (int i = wid; i < n; i += nw) {
        float xv = (lane < 6) ? xp[(size_t)i * 6 + lane] : 0.f;
        float acc = 0.f;
#pragma unroll
        for (int c = 0; c < 6; ++c) acc = fmaf(rdlane(xv, c), w[c], acc);
        float o = acc * dinv[i];
        float o0 = __shfl(o, sub * 4 + 0);
        float o1 = __shfl(o, sub * 4 + 1);
        float o2 = __shfl(o, sub * 4 + 2);
        float o3 = __shfl(o, sub * 4 + 3);
        if (lane < 16) sOut[(size_t)i * 16 + lane] = pk_fp8x4(o0, o1, o2, o3);
    }
}

// ------- FUSED gather+mm, fp8 rows (64B): 16 lanes x uint per row -----------
__global__ __launch_bounds__(256) void k_gathermm(
    const int* __restrict__ offI, const int* __restrict__ in_src,
    const float* __restrict__ dinv, const unsigned* __restrict__ sIn,
    const float* __restrict__ bias, const float* __restrict__ W,
    unsigned* __restrict__ sOut, int n) {
    int lane = threadIdx.x & 63;
    int sub = lane & 15, grp = lane >> 4;
    int wid = (blockIdx.x * blockDim.x + threadIdx.x) >> 6;
    int nw = (gridDim.x * blockDim.x) >> 6;
    float w[64];
#pragma unroll
    for (int c = 0; c < 64; ++c) w[c] = W[c * 64 + lane];
    float4 bb = ((const float4*)bias)[sub];

    for (int i = wid; i < n; i += nw) {
        unsigned su = sIn[(size_t)i * 16 + sub];
        float a0, a1, a2, a3;
        if (grp == 0) {
            floatx2 lo = __builtin_amdgcn_cvt_pk_f32_fp8(su, false);
            floatx2 hi = __builtin_amdgcn_cvt_pk_f32_fp8(su, true);
            a0 = lo.x; a1 = lo.y; a2 = hi.x; a3 = hi.y;
        } else { a0 = a1 = a2 = a3 = 0.f; }
        int b0 = offI[i], e0 = offI[i + 1];
#pragma unroll 4
        for (int j = b0 + grp; j < e0; j += 4) {
            unsigned src = (unsigned)in_src[j];
            unsigned u = sIn[(size_t)src * 16 + sub];
            floatx2 lo = __builtin_amdgcn_cvt_pk_f32_fp8(u, false);
            floatx2 hi = __builtin_amdgcn_cvt_pk_f32_fp8(u, true);
            a0 += lo.x; a1 += lo.y; a2 += hi.x; a3 += hi.y;
        }
        a0 += __shfl_xor(a0, 16); a1 += __shfl_xor(a1, 16);
        a2 += __shfl_xor(a2, 16); a3 += __shfl_xor(a3, 16);
        a0 += __shfl_xor(a0, 32); a1 += __shfl_xor(a1, 32);
        a2 += __shfl_xor(a2, 32); a3 += __shfl_xor(a3, 32);

        float dv = dinv[i];
        float h0 = fmaxf(fmaf(a0, dv, bb.x), 0.f);
        float h1 = fmaxf(fmaf(a1, dv, bb.y), 0.f);
        float h2 = fmaxf(fmaf(a2, dv, bb.z), 0.f);
        float h3 = fmaxf(fmaf(a3, dv, bb.w), 0.f);
        float o = 0.f;
#pragma unroll
        for (int g = 0; g < 16; ++g) {
            o = fmaf(rdlane(h0, g), w[g * 4 + 0], o);
            o = fmaf(rdlane(h1, g), w[g * 4 + 1], o);
            o = fmaf(rdlane(h2, g), w[g * 4 + 2], o);
            o = fmaf(rdlane(h3, g), w[g * 4 + 3], o);
        }
        o *= dv;
        float o0 = __shfl(o, sub * 4 + 0);
        float o1 = __shfl(o, sub * 4 + 1);
        float o2 = __shfl(o, sub * 4 + 2);
        float o3 = __shfl(o, sub * 4 + 3);
        if (lane < 16) sOut[(size_t)i * 16 + lane] = pk_fp8x4(o0, o1, o2, o3);
    }
}

// ------- FUSED final gather + b3 + pooled sum/sumsq, fp8 rows ---------------
__global__ __launch_bounds__(256) void k_gatherreduce(
    const int* __restrict__ offI, const int* __restrict__ in_src,
    const float* __restrict__ dinv, const unsigned* __restrict__ sIn,
    const float* __restrict__ b3, double* __restrict__ sums, int n) {
    int lane = threadIdx.x & 63;
    int sub = lane & 15, grp = lane >> 4;
    int wv = threadIdx.x >> 6;
    int wid = (blockIdx.x * blockDim.x + threadIdx.x) >> 6;
    int nw = (gridDim.x * blockDim.x) >> 6;
    float4 bb = ((const float4*)b3)[sub];
    double s0 = 0.0, s1 = 0.0, s2_ = 0.0, s3 = 0.0;
    double q0 = 0.0, q1 = 0.0, q2 = 0.0, q3 = 0.0;

    for (int i = wid; i < n; i += nw) {
        unsigned su = sIn[(size_t)i * 16 + sub];
        float a0, a1, a2, a3;
        if (grp == 0) {
            floatx2 lo = __builtin_amdgcn_cvt_pk_f32_fp8(su, false);
            floatx2 hi = __builtin_amdgcn_cvt_pk_f32_fp8(su, true);
            a0 = lo.x; a1 = lo.y; a2 = hi.x; a3 = hi.y;
        } else { a0 = a1 = a2 = a3 = 0.f; }
        int b0 = offI[i], e0 = offI[i + 1];
#pragma unroll 4
        for (int j = b0 + grp; j < e0; j += 4) {
            unsigned src = (unsigned)in_src[j];
            unsigned u = sIn[(size_t)src * 16 + sub];
            floatx2 lo = __builtin_amdgcn_cvt_pk_f32_fp8(u, false);
            floatx2 hi = __builtin_amdgcn_cvt_pk_f32_fp8(u, true);
            a0 += lo.x; a1 += lo.y; a2 += hi.x; a3 += hi.y;
        }
        a0 += __shfl_xor(a0, 16); a1 += __shfl_xor(a1, 16);
        a2 += __shfl_xor(a2, 16); a3 += __shfl_xor(a3, 16);
        a0 += __shfl_xor(a0, 32); a1 += __shfl_xor(a1, 32);
        a2 += __shfl_xor(a2, 32); a3 += __shfl_xor(a3, 32);

        float dv = dinv[i];
        float v0 = fmaf(a0, dv, bb.x);
        float v1 = fmaf(a1, dv, bb.y);
        float v2 = fmaf(a2, dv, bb.z);
        float v3 = fmaf(a3, dv, bb.w);
        s0 += v0; s1 += v1; s2_ += v2; s3 += v3;
        q0 += (double)v0 * v0; q1 += (double)v1 * v1;
        q2 += (double)v2 * v2; q3 += (double)v3 * v3;
    }
    __shared__ double shS[4 * 64], shQ[4 * 64];
    if (grp == 0) {
#pragma unroll
        for (int k = 0; k < 4; ++k) {
            double sk = (k == 0) ? s0 : (k == 1) ? s1 : (k == 2) ? s2_ : s3;
            double qk = (k == 0) ? q0 : (k == 1) ? q1 : (k == 2) ? q2 : q3;
            shS[wv * 64 + sub * 4 + k] = sk;
            shQ[wv * 64 + sub * 4 + k] = qk;
        }
    }
    __syncthreads();
    if (wv == 0) {
        double a = shS[lane] + shS[64 + lane] + shS[128 + lane] + shS[192 + lane];
        double c = shQ[lane] + shQ[64 + lane] + shQ[128 + lane] + shQ[192 + lane];
        unsafeAtomicAdd(&sums[lane], a);
        unsafeAtomicAdd(&sums[64 + lane], c);
    }
}

// ---------------- head MLP + sigmoid (single block) -------------------------
__global__ void k_head(const double* __restrict__ sums,
                       const float* __restrict__ Wp1, const float* __restrict__ bp1,
                       const float* __restrict__ Wp2, const float* __restrict__ bp2,
                       const float* __restrict__ Wp3, const float* __restrict__ bp3,
                       float* __restrict__ out, int n) {
    __shared__ float comb[192], p1[64], p2[32];
    int t = threadIdx.x;
    if (t < 64) {
        double s = sums[t], s2 = sums[64 + t];
        double m = s / n;
        double var = (s2 - s * s / n) / (double)(n - 1);
        float mf = (float)m;
        float sd = (float)sqrt(var > 0.0 ? var : 0.0);
        comb[t] = mf;
        comb[64 + t] = mf;
        comb[128 + t] = sd;
    }
    __syncthreads();
    if (t < 64) {
        float acc = bp1[t];
        for (int k = 0; k < 192; ++k) acc = fmaf(comb[k], Wp1[k * 64 + t], acc);
        p1[t] = fmaxf(acc, 0.f);
    }
    __syncthreads();
    if (t < 32) {
        float acc = bp2[t];
        for (int k = 0; k < 64; ++k) acc = fmaf(p1[k], Wp2[k * 32 + t], acc);
        p2[t] = fmaxf(acc, 0.f);
    }
    __syncthreads();
    if (t == 0) {
        float acc = bp3[0];
        for (int k = 0; k < 32; ++k) acc = fmaf(p2[k], Wp3[k], acc);
        out[0] = 1.f / (1.f + expf(-acc));
    }
}

static inline char* align16(char* p) {
    return (char*)(((uintptr_t)p + 15) & ~(uintptr_t)15);
}

extern "C" void kernel_launch(void* const* d_in, const int* in_sizes, int n_in,
                              void* d_out, int out_size, void* d_ws, size_t ws_size,
                              hipStream_t stream) {
    const float* x   = (const float*)d_in[0];
    const int*   ei  = (const int*)d_in[1];
    const float* ea  = (const float*)d_in[2];
    const float* W1  = (const float*)d_in[3];
    const float* b1  = (const float*)d_in[4];
    const float* W2  = (const float*)d_in[5];
    const float* b2  = (const float*)d_in[6];
    const float* W3  = (const float*)d_in[7];
    const float* b3  = (const float*)d_in[8];
    const float* We1 = (const float*)d_in[9];
    const float* be1 = (const float*)d_in[10];
    const float* We2 = (const float*)d_in[11];
    const float* be2 = (const float*)d_in[12];
    const float* Wp1 = (const float*)d_in[13];
    const float* bp1 = (const float*)d_in[14];
    const float* Wp2 = (const float*)d_in[15];
    const float* bp2 = (const float*)d_in[16];
    const float* Wp3 = (const float*)d_in[17];
    const float* bp3 = (const float*)d_in[18];

    const int N = in_sizes[0] / 6;
    const int E = in_sizes[1] / 2;
    const int epb = (E + NBLKA - 1) / NBLKA;
    const int HSZ = NB * NBLKA;                 // 25088
    const int nScan = (HSZ + 511) / 512;        // 49
    const size_t SB = (size_t)N * 64;           // fp8 table = 6.4MB

    // ---- workspace layout (~74 MB) ----
    char* p = (char*)d_ws;
    double* sums = (double*)p;          p = align16(p + 128 * sizeof(double));
    int* inTot = (int*)p;               p = align16(p + NB * 4);
    int* inBase = (int*)p;              p = align16(p + NB * 4);
    int* bsum = (int*)p;                p = align16(p + 512 * 4);
    int* h = (int*)p;                   p = align16(p + (size_t)HSZ * 4);
    uint2* efp = (uint2*)p;             p = align16(p + (size_t)E * 8);
    float* xp = (float*)p;              p = align16(p + (size_t)N * 6 * 4);
    float* dinv = (float*)p;            p = align16(p + (size_t)N * 4);
    int* offI = (int*)p;                p = align16(p + ((size_t)N + 1) * 4);
    int* in_src = (int*)p;              p = align16(p + (size_t)E * 4);
    // U: records (2E*16B = 51.2MB) die after k_B; sbufA/B reborn inside
    char* u = p;
    uint4* rec = (uint4*)u;
    unsigned* sbufA = (unsigned*)u;
    unsigned* sbufB = (unsigned*)(u + ((SB + 15) & ~(size_t)15));

    dim3 blk(256);

    k_zero<<<dim3(1), dim3(512), 0, stream>>>(inTot, sums);
    k_A1<<<dim3(NBLKA), blk, 0, stream>>>(ei, ea, We1, be1, We2, be2, efp, h, inTot, E, epb);
    k_sc1<<<dim3(nScan), dim3(512), 0, stream>>>(h, bsum, HSZ);
    k_sc2<<<dim3(1), dim3(512), 0, stream>>>(bsum, nScan);
    k_sc3<<<dim3(nScan), dim3(512), 0, stream>>>(h, bsum, HSZ);
    k_scanIn<<<dim3(1), dim3(512), 0, stream>>>(inTot, inBase);
    k_A2<<<dim3(NBLKA), blk, 0, stream>>>(ei, efp, h, rec, E, epb);
    k_B<<<dim3(NB), dim3(512), 0, stream>>>(rec, h, inBase, x, xp, dinv, offI, in_src, E, N);

    // layer 1 matmul (sbufA aliases records — dead after k_B)
    k_mm1<<<dim3(1024), blk, 0, stream>>>(xp, W1, dinv, sbufA, N);
    // layers 2,3 fused gather+mm; final fused gather+reduce
    k_gathermm<<<dim3(2048), blk, 0, stream>>>(offI, in_src, dinv, sbufA, b1, W2, sbufB, N);
    k_gathermm<<<dim3(2048), blk, 0, stream>>>(offI, in_src, dinv, sbufB, b2, W3, sbufA, N);
    k_gatherreduce<<<dim3(2048), blk, 0, stream>>>(offI, in_src, dinv, sbufA, b3, sums, N);
    k_head<<<dim3(1), dim3(64), 0, stream>>>(sums, Wp1, bp1, Wp2, bp2, Wp3, bp3,
                                             (float*)d_out, N);
}

// Round 12
// 648.695 us; speedup vs baseline: 1.1607x; 1.1607x over previous
//
#include <hip/hip_runtime.h>
#include <hip/hip_bf16.h>
#include <stdint.h>

typedef float floatx2 __attribute__((ext_vector_type(2)));
typedef unsigned uint32x4 __attribute__((ext_vector_type(4)));
typedef float f32x4 __attribute__((ext_vector_type(4)));

__device__ __forceinline__ float rdlane(float v, int l) {
    return __uint_as_float(__builtin_amdgcn_readlane(__float_as_uint(v), l));
}
// pack floats -> fp8 e4m3 (HW cvt, RNE)
__device__ __forceinline__ unsigned pk_fp8x4(float a, float b, float c, float d) {
    int u = __builtin_amdgcn_cvt_pk_fp8_f32(a, b, 0, false);
    u = __builtin_amdgcn_cvt_pk_fp8_f32(c, d, u, true);
    return (unsigned)u;
}
__device__ __forceinline__ unsigned pk_fp8x2(float a, float b) {
    return (unsigned)__builtin_amdgcn_cvt_pk_fp8_f32(a, b, 0, false);
}

// ---------------- zero counters + pooled sums -------------------------------
__global__ void k_zero(int* __restrict__ cntO, int* __restrict__ cntI,
                       double* __restrict__ sums, int n) {
    int i = blockIdx.x * blockDim.x + threadIdx.x;
    if (i < 128) sums[i] = 0.0;
    if (i < n) { cntO[i] = 0; cntI[i] = 0; }
}

// ------- FUSED front: edge MLP (VALU) hides under 2 rank atomics/edge -------
__global__ __launch_bounds__(256) void k_front(
    const int* __restrict__ ei, const float* __restrict__ ea,
    const float* __restrict__ We1, const float* __restrict__ be1,
    const float* __restrict__ We2, const float* __restrict__ be2,
    uint2* __restrict__ efp, int* __restrict__ cntO, int* __restrict__ cntI,
    int* __restrict__ rankS, int* __restrict__ rankD, int E) {
    __shared__ float sWe1[128], sbe1[64], sWe2[64 * 6], sbe2[6];
    int t = threadIdx.x;
    if (t < 128) sWe1[t] = We1[t];
    if (t < 64) {
        sbe1[t] = be1[t];
#pragma unroll
        for (int c = 0; c < 6; ++c) sWe2[t * 6 + c] = We2[t * 64 + c];
    }
    if (t < 6) sbe2[t] = be2[t];
    __syncthreads();

    int e = blockIdx.x * blockDim.x + t;
    if (e >= E) return;

    int s = ei[e], d = ei[E + e];
    int rs = atomicAdd(&cntO[s], 1);      // issue early; MLP overlaps RMW
    int rd = atomicAdd(&cntI[d], 1);

    float2 aa = ((const float2*)ea)[e];
    float acc[6];
#pragma unroll
    for (int c = 0; c < 6; ++c) acc[c] = sbe2[c];
#pragma unroll
    for (int j = 0; j < 64; ++j) {
        float h = fmaf(aa.x, sWe1[j], fmaf(aa.y, sWe1[64 + j], sbe1[j]));
        h = fmaxf(h, 0.f);
#pragma unroll
        for (int c = 0; c < 6; ++c) acc[c] = fmaf(h, sWe2[j * 6 + c], acc[c]);
    }
    efp[e] = make_uint2(pk_fp8x4(acc[0], acc[1], acc[2], acc[3]),
                        pk_fp8x2(acc[4], acc[5]));
    rankS[e] = rs;
    rankD[e] = rd;
}

// ---------------- fused int2 scan (3 passes) --------------------------------
__global__ __launch_bounds__(256) void k_scan1(const int* __restrict__ cntO,
                                               const int* __restrict__ cntI,
                                               int2* __restrict__ bsum, int n) {
    __shared__ int2 l[256];
    int i = blockIdx.x * 256 + threadIdx.x;
    l[threadIdx.x] = (i < n) ? make_int2(cntO[i], cntI[i]) : make_int2(0, 0);
    __syncthreads();
    for (int s = 128; s > 0; s >>= 1) {
        if (threadIdx.x < s) {
            l[threadIdx.x].x += l[threadIdx.x + s].x;
            l[threadIdx.x].y += l[threadIdx.x + s].y;
        }
        __syncthreads();
    }
    if (threadIdx.x == 0) bsum[blockIdx.x] = l[0];
}
__global__ __launch_bounds__(512) void k_scan2(int2* __restrict__ bsum, int nb,
                                               int* __restrict__ offON,
                                               int* __restrict__ offIN) {
    __shared__ int2 l[512];
    int t = threadIdx.x;
    int2 v = (t < nb) ? bsum[t] : make_int2(0, 0);
    l[t] = v;
    __syncthreads();
    for (int s = 1; s < 512; s <<= 1) {
        int2 tmp = (t >= s) ? l[t - s] : make_int2(0, 0);
        __syncthreads();
        l[t].x += tmp.x; l[t].y += tmp.y;
        __syncthreads();
    }
    if (t < nb) bsum[t] = make_int2(l[t].x - v.x, l[t].y - v.y);
    if (t == 511) { *offON = l[511].x; *offIN = l[511].y; }
}
__global__ __launch_bounds__(256) void k_scan3off(const int* __restrict__ cntO,
                                                  const int* __restrict__ cntI,
                                                  const int2* __restrict__ bsum,
                                                  int* __restrict__ offO,
                                                  int* __restrict__ offI, int n) {
    __shared__ int2 l[256];
    int i = blockIdx.x * 256 + threadIdx.x;
    int2 v = (i < n) ? make_int2(cntO[i], cntI[i]) : make_int2(0, 0);
    l[threadIdx.x] = v;
    __syncthreads();
    for (int s = 1; s < 256; s <<= 1) {
        int2 tmp = (threadIdx.x >= (unsigned)s) ? l[threadIdx.x - s] : make_int2(0, 0);
        __syncthreads();
        l[threadIdx.x].x += tmp.x; l[threadIdx.x].y += tmp.y;
        __syncthreads();
    }
    if (i < n) {
        int2 bs = bsum[blockIdx.x];
        offO[i] = l[threadIdx.x].x - v.x + bs.x;
        offI[i] = l[threadIdx.x].y - v.y + bs.y;
    }
}

// ------- CSR placement: 2 scattered stores/edge, fp8 ef embedded ------------
__global__ __launch_bounds__(256) void k_place(const int* __restrict__ ei,
                                               const int* __restrict__ rankS,
                                               const int* __restrict__ rankD,
                                               const int* __restrict__ offO,
                                               const int* __restrict__ offI,
                                               const uint2* __restrict__ efp,
                                               uint2* __restrict__ out_rec,
                                               uint4* __restrict__ in_rec, int E) {
    int e = blockIdx.x * blockDim.x + threadIdx.x;
    if (e >= E) return;
    int s = ei[e], d = ei[E + e];
    uint2 f = efp[e];
    out_rec[offO[s] + rankS[e]] = f;
    in_rec[offI[d] + rankD[e]] = make_uint4((unsigned)s, f.x, f.y, 0u);
}

// ------- per node: nef sums + dinv + in_src emit + FUSED layer-1 matmul -----
__global__ __launch_bounds__(256) void k_nefmm1(
    const int* __restrict__ offO, const uint2* __restrict__ out_rec,
    const int* __restrict__ offI, const uint4* __restrict__ in_rec,
    const float* __restrict__ x, const float* __restrict__ W1,
    float* __restrict__ dinv, int* __restrict__ in_src,
    unsigned* __restrict__ sLo, unsigned* __restrict__ sHi, int n) {
    __shared__ float sW1[384];
    int t = threadIdx.x;
    for (int idx = t; idx < 384; idx += 256) sW1[idx] = W1[idx];
    __syncthreads();

    int i = blockIdx.x * blockDim.x + t;
    if (i >= n) return;
    int bo = offO[i], eo = offO[i + 1];
    int bi = offI[i], eiN = offI[i + 1];
    float a0 = 0.f, a1 = 0.f, a2 = 0.f, a3 = 0.f, a4 = 0.f, a5 = 0.f;
    for (int j = bo; j < eo; ++j) {
        uint2 q = out_rec[j];
        floatx2 p01 = __builtin_amdgcn_cvt_pk_f32_fp8(q.x, false);
        floatx2 p23 = __builtin_amdgcn_cvt_pk_f32_fp8(q.x, true);
        floatx2 p45 = __builtin_amdgcn_cvt_pk_f32_fp8(q.y, false);
        a0 += p01.x; a1 += p01.y; a2 += p23.x;
        a3 += p23.y; a4 += p45.x; a5 += p45.y;
    }
    for (int j = bi; j < eiN; ++j) {
        uint4 r = in_rec[j];
        __builtin_nontemporal_store((int)r.x, in_src + j);   // compact stream
        floatx2 p01 = __builtin_amdgcn_cvt_pk_f32_fp8(r.y, false);
        floatx2 p23 = __builtin_amdgcn_cvt_pk_f32_fp8(r.y, true);
        floatx2 p45 = __builtin_amdgcn_cvt_pk_f32_fp8(r.z, false);
        a0 += p01.x; a1 += p01.y; a2 += p23.x;
        a3 += p23.y; a4 += p45.x; a5 += p45.y;
    }
    int indeg = eiN - bi;
    float degf = (float)((eo - bo) + indeg);
    float inv = 0.5f / fmaxf(degf, 1.f);
    const float2* xr = (const float2*)(x + (size_t)i * 6);
    float2 x01 = xr[0], x23 = xr[1], x45 = xr[2];
    float xp0 = x01.x + a0 * inv, xp1 = x01.y + a1 * inv;
    float xp2 = x23.x + a2 * inv, xp3 = x23.y + a3 * inv;
    float xp4 = x45.x + a4 * inv, xp5 = x45.y + a5 * inv;
    float dv = 1.f / sqrtf(1.f + (float)indeg);
    dinv[i] = dv;

    // layer 1: s1 = fp8(dv * (xp @ W1)); split lo/hi tables
    unsigned u[8];
#pragma unroll
    for (int c4 = 0; c4 < 8; ++c4) {
        float tv[4];
#pragma unroll
        for (int k = 0; k < 4; ++k) {
            int c = c4 * 4 + k;
            float v = xp0 * sW1[c] + xp1 * sW1[64 + c] + xp2 * sW1[128 + c]
                    + xp3 * sW1[192 + c] + xp4 * sW1[256 + c] + xp5 * sW1[320 + c];
            tv[k] = v * dv;
        }
        u[c4] = pk_fp8x4(tv[0], tv[1], tv[2], tv[3]);
    }
    {
        uint32x4 v0 = {u[0], u[1], u[2], u[3]};
        uint32x4 v1 = {u[4], u[5], u[6], u[7]};
        __builtin_nontemporal_store(v0, (uint32x4*)(sLo + (size_t)i * 8));
        __builtin_nontemporal_store(v1, (uint32x4*)(sLo + (size_t)i * 8) + 1);
    }
#pragma unroll
    for (int c4 = 0; c4 < 8; ++c4) {
        float tv[4];
#pragma unroll
        for (int k = 0; k < 4; ++k) {
            int c = 32 + c4 * 4 + k;
            float v = xp0 * sW1[c] + xp1 * sW1[64 + c] + xp2 * sW1[128 + c]
                    + xp3 * sW1[192 + c] + xp4 * sW1[256 + c] + xp5 * sW1[320 + c];
            tv[k] = v * dv;
        }
        u[c4] = pk_fp8x4(tv[0], tv[1], tv[2], tv[3]);
    }
    {
        uint32x4 v0 = {u[0], u[1], u[2], u[3]};
        uint32x4 v1 = {u[4], u[5], u[6], u[7]};
        __builtin_nontemporal_store(v0, (uint32x4*)(sHi + (size_t)i * 8));
        __builtin_nontemporal_store(v1, (uint32x4*)(sHi + (size_t)i * 8) + 1);
    }
}

// ------- gather LO half: 3.2MB table (L2-resident), agg f32 out (NT) --------
__global__ __launch_bounds__(256) void k_gather_lo(
    const int* __restrict__ offI, const int* __restrict__ in_src,
    const unsigned* __restrict__ sLo, float* __restrict__ agg, int n) {
    int lane = threadIdx.x & 63;
    int sub = lane & 7, grp = lane >> 3;
    int wid = (blockIdx.x * blockDim.x + threadIdx.x) >> 6;
    int nw = (gridDim.x * blockDim.x) >> 6;
    for (int i = wid; i < n; i += nw) {
        unsigned su = sLo[(size_t)i * 8 + sub];
        float a0, a1, a2, a3;
        if (grp == 0) {
            floatx2 lo = __builtin_amdgcn_cvt_pk_f32_fp8(su, false);
            floatx2 hi = __builtin_amdgcn_cvt_pk_f32_fp8(su, true);
            a0 = lo.x; a1 = lo.y; a2 = hi.x; a3 = hi.y;
        } else { a0 = a1 = a2 = a3 = 0.f; }
        int b0 = offI[i], e0 = offI[i + 1];
#pragma unroll 4
        for (int j = b0 + grp; j < e0; j += 8) {
            unsigned src = (unsigned)__builtin_nontemporal_load(in_src + j);
            unsigned u = sLo[(size_t)src * 8 + sub];
            floatx2 lo = __builtin_amdgcn_cvt_pk_f32_fp8(u, false);
            floatx2 hi = __builtin_amdgcn_cvt_pk_f32_fp8(u, true);
            a0 += lo.x; a1 += lo.y; a2 += hi.x; a3 += hi.y;
        }
        a0 += __shfl_xor(a0, 8);  a1 += __shfl_xor(a1, 8);
        a2 += __shfl_xor(a2, 8);  a3 += __shfl_xor(a3, 8);
        a0 += __shfl_xor(a0, 16); a1 += __shfl_xor(a1, 16);
        a2 += __shfl_xor(a2, 16); a3 += __shfl_xor(a3, 16);
        a0 += __shfl_xor(a0, 32); a1 += __shfl_xor(a1, 32);
        a2 += __shfl_xor(a2, 32); a3 += __shfl_xor(a3, 32);
        if (lane < 8) {
            f32x4 v = {a0, a1, a2, a3};
            __builtin_nontemporal_store(v, (f32x4*)(agg + (size_t)i * 32) + lane);
        }
    }
}

// ------- gather HI half + combine + relu(+bias) + matmul -> split fp8 out ---
__global__ __launch_bounds__(256) void k_gathermm_hi(
    const int* __restrict__ offI, const int* __restrict__ in_src,
    const float* __restrict__ dinv, const unsigned* __restrict__ sHiIn,
    const float* __restrict__ agg, const float* __restrict__ bias,
    const float* __restrict__ W,
    unsigned* __restrict__ sLoOut, unsigned* __restrict__ sHiOut, int n) {
    int lane = threadIdx.x & 63;
    int sub = lane & 7, grp = lane >> 3;
    int wid = (blockIdx.x * blockDim.x + threadIdx.x) >> 6;
    int nw = (gridDim.x * blockDim.x) >> 6;
    float w[64];
#pragma unroll
    for (int c = 0; c < 64; ++c) w[c] = W[c * 64 + lane];
    float blo = bias[lane & 31];
    float4 bh = ((const float4*)bias)[8 + sub];

    for (int i = wid; i < n; i += nw) {
        unsigned su = sHiIn[(size_t)i * 8 + sub];
        float a0, a1, a2, a3;
        if (grp == 0) {
            floatx2 lo = __builtin_amdgcn_cvt_pk_f32_fp8(su, false);
            floatx2 hi = __builtin_amdgcn_cvt_pk_f32_fp8(su, true);
            a0 = lo.x; a1 = lo.y; a2 = hi.x; a3 = hi.y;
        } else { a0 = a1 = a2 = a3 = 0.f; }
        int b0 = offI[i], e0 = offI[i + 1];
#pragma unroll 4
        for (int j = b0 + grp; j < e0; j += 8) {
            unsigned src = (unsigned)__builtin_nontemporal_load(in_src + j);
            unsigned u = sHiIn[(size_t)src * 8 + sub];
            floatx2 lo = __builtin_amdgcn_cvt_pk_f32_fp8(u, false);
            floatx2 hi = __builtin_amdgcn_cvt_pk_f32_fp8(u, true);
            a0 += lo.x; a1 += lo.y; a2 += hi.x; a3 += hi.y;
        }
        a0 += __shfl_xor(a0, 8);  a1 += __shfl_xor(a1, 8);
        a2 += __shfl_xor(a2, 8);  a3 += __shfl_xor(a3, 8);
        a0 += __shfl_xor(a0, 16); a1 += __shfl_xor(a1, 16);
        a2 += __shfl_xor(a2, 16); a3 += __shfl_xor(a3, 16);
        a0 += __shfl_xor(a0, 32); a1 += __shfl_xor(a1, 32);
        a2 += __shfl_xor(a2, 32); a3 += __shfl_xor(a3, 32);

        float alo = __builtin_nontemporal_load(agg + (size_t)i * 32 + (lane & 31));
        float dv = dinv[i];
        float hlo = fmaxf(fmaf(alo, dv, blo), 0.f);
        float h0 = fmaxf(fmaf(a0, dv, bh.x), 0.f);
        float h1 = fmaxf(fmaf(a1, dv, bh.y), 0.f);
        float h2 = fmaxf(fmaf(a2, dv, bh.z), 0.f);
        float h3 = fmaxf(fmaf(a3, dv, bh.w), 0.f);
        float o = 0.f;
#pragma unroll
        for (int f = 0; f < 32; ++f) o = fmaf(rdlane(hlo, f), w[f], o);
#pragma unroll
        for (int g = 0; g < 8; ++g) {
            o = fmaf(rdlane(h0, g), w[32 + g * 4 + 0], o);
            o = fmaf(rdlane(h1, g), w[32 + g * 4 + 1], o);
            o = fmaf(rdlane(h2, g), w[32 + g * 4 + 2], o);
            o = fmaf(rdlane(h3, g), w[32 + g * 4 + 3], o);
        }
        o *= dv;
        int s16 = lane & 15;
        float o0 = __shfl(o, s16 * 4 + 0);
        float o1 = __shfl(o, s16 * 4 + 1);
        float o2 = __shfl(o, s16 * 4 + 2);
        float o3 = __shfl(o, s16 * 4 + 3);
        unsigned u = pk_fp8x4(o0, o1, o2, o3);
        if (lane < 8) __builtin_nontemporal_store(u, sLoOut + (size_t)i * 8 + lane);
        else if (lane < 16) __builtin_nontemporal_store(u, sHiOut + (size_t)i * 8 + lane - 8);
    }
}

// ------- gather HI half + combine + b3 + pooled sum/sumsq -------------------
__global__ __launch_bounds__(256) void k_gatherreduce_hi(
    const int* __restrict__ offI, const int* __restrict__ in_src,
    const float* __restrict__ dinv, const unsigned* __restrict__ sHiIn,
    const float* __restrict__ agg, const float* __restrict__ b3,
    double* __restrict__ sums, int n) {
    int lane = threadIdx.x & 63;
    int sub = lane & 7, grp = lane >> 3;
    int wv = threadIdx.x >> 6;
    int wid = (blockIdx.x * blockDim.x + threadIdx.x) >> 6;
    int nw = (gridDim.x * blockDim.x) >> 6;
    float blo = b3[lane & 31];
    float4 bh = ((const float4*)b3)[8 + sub];
    double sL = 0.0, qL = 0.0;
    double sH0 = 0.0, sH1 = 0.0, sH2 = 0.0, sH3 = 0.0;
    double qH0 = 0.0, qH1 = 0.0, qH2 = 0.0, qH3 = 0.0;

    for (int i = wid; i < n; i += nw) {
        unsigned su = sHiIn[(size_t)i * 8 + sub];
        float a0, a1, a2, a3;
        if (grp == 0) {
            floatx2 lo = __builtin_amdgcn_cvt_pk_f32_fp8(su, false);
            floatx2 hi = __builtin_amdgcn_cvt_pk_f32_fp8(su, true);
            a0 = lo.x; a1 = lo.y; a2 = hi.x; a3 = hi.y;
        } else { a0 = a1 = a2 = a3 = 0.f; }
        int b0 = offI[i], e0 = offI[i + 1];
#pragma unroll 4
        for (int j = b0 + grp; j < e0; j += 8) {
            unsigned src = (unsigned)__builtin_nontemporal_load(in_src + j);
            unsigned u = sHiIn[(size_t)src * 8 + sub];
            floatx2 lo = __builtin_amdgcn_cvt_pk_f32_fp8(u, false);
            floatx2 hi = __builtin_amdgcn_cvt_pk_f32_fp8(u, true);
            a0 += lo.x; a1 += lo.y; a2 += hi.x; a3 += hi.y;
        }
        a0 += __shfl_xor(a0, 8);  a1 += __shfl_xor(a1, 8);
        a2 += __shfl_xor(a2, 8);  a3 += __shfl_xor(a3, 8);
        a0 += __shfl_xor(a0, 16); a1 += __shfl_xor(a1, 16);
        a2 += __shfl_xor(a2, 16); a3 += __shfl_xor(a3, 16);
        a0 += __shfl_xor(a0, 32); a1 += __shfl_xor(a1, 32);
        a2 += __shfl_xor(a2, 32); a3 += __shfl_xor(a3, 32);

        float alo = __builtin_nontemporal_load(agg + (size_t)i * 32 + (lane & 31));
        float dv = dinv[i];
        float vlo = fmaf(alo, dv, blo);
        float v0 = fmaf(a0, dv, bh.x);
        float v1 = fmaf(a1, dv, bh.y);
        float v2 = fmaf(a2, dv, bh.z);
        float v3 = fmaf(a3, dv, bh.w);
        sL += vlo; qL += (double)vlo * vlo;
        sH0 += v0; qH0 += (double)v0 * v0;
        sH1 += v1; qH1 += (double)v1 * v1;
        sH2 += v2; qH2 += (double)v2 * v2;
        sH3 += v3; qH3 += (double)v3 * v3;
    }
    __shared__ double shS[4 * 64], shQ[4 * 64];
    if (lane < 32) { shS[wv * 64 + lane] = sL; shQ[wv * 64 + lane] = qL; }
    if (lane < 8) {
        shS[wv * 64 + 32 + lane * 4 + 0] = sH0; shQ[wv * 64 + 32 + lane * 4 + 0] = qH0;
        shS[wv * 64 + 32 + lane * 4 + 1] = sH1; shQ[wv * 64 + 32 + lane * 4 + 1] = qH1;
        shS[wv * 64 + 32 + lane * 4 + 2] = sH2; shQ[wv * 64 + 32 + lane * 4 + 2] = qH2;
        shS[wv * 64 + 32 + lane * 4 + 3] = sH3; shQ[wv * 64 + 32 + lane * 4 + 3] = qH3;
    }
    __syncthreads();
    if (wv == 0) {
        double a = shS[lane] + shS[64 + lane] + shS[128 + lane] + shS[192 + lane];
        double c = shQ[lane] + shQ[64 + lane] + shQ[128 + lane] + shQ[192 + lane];
        unsafeAtomicAdd(&sums[lane], a);
        unsafeAtomicAdd(&sums[64 + lane], c);
    }
}

// ---------------- head MLP + sigmoid (single block) -------------------------
__global__ void k_head(const double* __restrict__ sums,
                       const float* __restrict__ Wp1, const float* __restrict__ bp1,
                       const float* __restrict__ Wp2, const float* __restrict__ bp2,
                       const float* __restrict__ Wp3, const float* __restrict__ bp3,
                       float* __restrict__ out, int n) {
    __shared__ float comb[192], p1[64], p2[32];
    int t = threadIdx.x;
    if (t < 64) {
        double s = sums[t], s2 = sums[64 + t];
        double m = s / n;
        double var = (s2 - s * s / n) / (double)(n - 1);
        float mf = (float)m;
        float sd = (float)sqrt(var > 0.0 ? var : 0.0);
        comb[t] = mf;
        comb[64 + t] = mf;
        comb[128 + t] = sd;
    }
    __syncthreads();
    if (t < 64) {
        float acc = bp1[t];
        for (int k = 0; k < 192; ++k) acc = fmaf(comb[k], Wp1[k * 64 + t], acc);
        p1[t] = fmaxf(acc, 0.f);
    }
    __syncthreads();
    if (t < 32) {
        float acc = bp2[t];
        for (int k = 0; k < 64; ++k) acc = fmaf(p1[k], Wp2[k * 32 + t], acc);
        p2[t] = fmaxf(acc, 0.f);
    }
    __syncthreads();
    if (t == 0) {
        float acc = bp3[0];
        for (int k = 0; k < 32; ++k) acc = fmaf(p2[k], Wp3[k], acc);
        out[0] = 1.f / (1.f + expf(-acc));
    }
}

static inline char* align16(char* p) {
    return (char*)(((uintptr_t)p + 15) & ~(uintptr_t)15);
}

extern "C" void kernel_launch(void* const* d_in, const int* in_sizes, int n_in,
                              void* d_out, int out_size, void* d_ws, size_t ws_size,
                              hipStream_t stream) {
    const float* x   = (const float*)d_in[0];
    const int*   ei  = (const int*)d_in[1];
    const float* ea  = (const float*)d_in[2];
    const float* W1  = (const float*)d_in[3];
    const float* b1  = (const float*)d_in[4];
    const float* W2  = (const float*)d_in[5];
    const float* b2  = (const float*)d_in[6];
    const float* W3  = (const float*)d_in[7];
    const float* b3  = (const float*)d_in[8];
    const float* We1 = (const float*)d_in[9];
    const float* be1 = (const float*)d_in[10];
    const float* We2 = (const float*)d_in[11];
    const float* be2 = (const float*)d_in[12];
    const float* Wp1 = (const float*)d_in[13];
    const float* bp1 = (const float*)d_in[14];
    const float* Wp2 = (const float*)d_in[15];
    const float* bp2 = (const float*)d_in[16];
    const float* Wp3 = (const float*)d_in[17];
    const float* bp3 = (const float*)d_in[18];

    const int N = in_sizes[0] / 6;
    const int E = in_sizes[1] / 2;
    const int nbN = (N + 255) / 256;
    const int nbE = (E + 255) / 256;
    const size_t HT = ((size_t)N * 32 + 15) & ~(size_t)15;  // one half-table 3.2MB

    // ---- workspace layout (~72 MB) ----
    char* p = (char*)d_ws;
    double* sums = (double*)p;          p = align16(p + 128 * sizeof(double));
    int* cntO = (int*)p;                p = align16(p + (size_t)N * 4);
    int* cntI = (int*)p;                p = align16(p + (size_t)N * 4);
    int* offO = (int*)p;                p = align16(p + ((size_t)N + 1) * 4);
    int* offI = (int*)p;                p = align16(p + ((size_t)N + 1) * 4);
    int2* bsum = (int2*)p;              p = align16(p + 512 * 8);
    float* dinv = (float*)p;            p = align16(p + (size_t)N * 4);
    int* in_src = (int*)p;              p = align16(p + (size_t)E * 4);
    uint4* in_rec = (uint4*)p;          p = align16(p + (size_t)E * 16);
    // U1: rankS/rankD (E*4 each) die after k_place -> sA_lo/hi, sB_lo/hi
    char* u1 = p;                       p = align16(p + 4 * HT);
    int* rankS = (int*)u1;
    int* rankD = (int*)(u1 + 2 * HT);
    unsigned* sA_lo = (unsigned*)u1;
    unsigned* sA_hi = (unsigned*)(u1 + HT);
    unsigned* sB_lo = (unsigned*)(u1 + 2 * HT);
    unsigned* sB_hi = (unsigned*)(u1 + 3 * HT);
    // U2: efp (E*8) + out_rec (E*8) die after k_nefmm1 -> agg (N*32*4=12.8MB)
    char* u2 = p;
    uint2* efp = (uint2*)u2;
    uint2* out_rec = (uint2*)(u2 + (size_t)E * 8);
    float* agg = (float*)u2;

    dim3 blk(256);

    k_zero<<<dim3(nbN), blk, 0, stream>>>(cntO, cntI, sums, N);
    k_front<<<dim3(nbE), blk, 0, stream>>>(ei, ea, We1, be1, We2, be2,
                                           efp, cntO, cntI, rankS, rankD, E);
    k_scan1<<<dim3(nbN), blk, 0, stream>>>(cntO, cntI, bsum, N);
    k_scan2<<<dim3(1), dim3(512), 0, stream>>>(bsum, nbN, offO + N, offI + N);
    k_scan3off<<<dim3(nbN), blk, 0, stream>>>(cntO, cntI, bsum, offO, offI, N);
    k_place<<<dim3(nbE), blk, 0, stream>>>(ei, rankS, rankD, offO, offI, efp,
                                           out_rec, in_rec, E);
    k_nefmm1<<<dim3(nbN), blk, 0, stream>>>(offO, out_rec, offI, in_rec, x, W1,
                                            dinv, in_src, sA_lo, sA_hi, N);

    // layer 2
    k_gather_lo<<<dim3(2048), blk, 0, stream>>>(offI, in_src, sA_lo, agg, N);
    k_gathermm_hi<<<dim3(2048), blk, 0, stream>>>(offI, in_src, dinv, sA_hi, agg,
                                                  b1, W2, sB_lo, sB_hi, N);
    // layer 3
    k_gather_lo<<<dim3(2048), blk, 0, stream>>>(offI, in_src, sB_lo, agg, N);
    k_gathermm_hi<<<dim3(2048), blk, 0, stream>>>(offI, in_src, dinv, sB_hi, agg,
                                                  b2, W3, sA_lo, sA_hi, N);
    // final aggregation + pooled reduce
    k_gather_lo<<<dim3(2048), blk, 0, stream>>>(offI, in_src, sA_lo, agg, N);
    k_gatherreduce_hi<<<dim3(2048), blk, 0, stream>>>(offI, in_src, dinv, sA_hi, agg,
                                                      b3, sums, N);
    k_head<<<dim3(1), dim3(64), 0, stream>>>(sums, Wp1, bp1, Wp2, bp2, Wp3, bp3,
                                             (float*)d_out, N);
}

// Round 13
// 606.455 us; speedup vs baseline: 1.2415x; 1.0697x over previous
//
#include <hip/hip_runtime.h>
#include <hip/hip_bf16.h>
#include <stdint.h>

typedef float floatx2 __attribute__((ext_vector_type(2)));
typedef unsigned uint32x4 __attribute__((ext_vector_type(4)));

__device__ __forceinline__ float rdlane(float v, int l) {
    return __uint_as_float(__builtin_amdgcn_readlane(__float_as_uint(v), l));
}
// pack floats -> fp8 e4m3 (HW cvt, RNE)
__device__ __forceinline__ unsigned pk_fp8x4(float a, float b, float c, float d) {
    int u = __builtin_amdgcn_cvt_pk_fp8_f32(a, b, 0, false);
    u = __builtin_amdgcn_cvt_pk_fp8_f32(c, d, u, true);
    return (unsigned)u;
}
__device__ __forceinline__ unsigned pk_fp8x2(float a, float b) {
    return (unsigned)__builtin_amdgcn_cvt_pk_fp8_f32(a, b, 0, false);
}

// ---------------- zero counters + pooled sums -------------------------------
__global__ void k_zero(int* __restrict__ cntO, int* __restrict__ cntI,
                       double* __restrict__ sums, int n) {
    int i = blockIdx.x * blockDim.x + threadIdx.x;
    if (i < 128) sums[i] = 0.0;
    if (i < n) { cntO[i] = 0; cntI[i] = 0; }
}

// ------- FUSED front: edge MLP (VALU) hides under 2 rank atomics/edge -------
__global__ __launch_bounds__(256) void k_front(
    const int* __restrict__ ei, const float* __restrict__ ea,
    const float* __restrict__ We1, const float* __restrict__ be1,
    const float* __restrict__ We2, const float* __restrict__ be2,
    uint2* __restrict__ efp, int* __restrict__ cntO, int* __restrict__ cntI,
    int* __restrict__ rankS, int* __restrict__ rankD, int E) {
    __shared__ float sWe1[128], sbe1[64], sWe2[64 * 6], sbe2[6];
    int t = threadIdx.x;
    if (t < 128) sWe1[t] = We1[t];
    if (t < 64) {
        sbe1[t] = be1[t];
#pragma unroll
        for (int c = 0; c < 6; ++c) sWe2[t * 6 + c] = We2[t * 64 + c];
    }
    if (t < 6) sbe2[t] = be2[t];
    __syncthreads();

    int e = blockIdx.x * blockDim.x + t;
    if (e >= E) return;

    int s = ei[e], d = ei[E + e];
    int rs = atomicAdd(&cntO[s], 1);      // issue early; MLP overlaps RMW
    int rd = atomicAdd(&cntI[d], 1);

    float2 aa = ((const float2*)ea)[e];
    float acc[6];
#pragma unroll
    for (int c = 0; c < 6; ++c) acc[c] = sbe2[c];
#pragma unroll
    for (int j = 0; j < 64; ++j) {
        float h = fmaf(aa.x, sWe1[j], fmaf(aa.y, sWe1[64 + j], sbe1[j]));
        h = fmaxf(h, 0.f);
#pragma unroll
        for (int c = 0; c < 6; ++c) acc[c] = fmaf(h, sWe2[j * 6 + c], acc[c]);
    }
    efp[e] = make_uint2(pk_fp8x4(acc[0], acc[1], acc[2], acc[3]),
                        pk_fp8x2(acc[4], acc[5]));
    rankS[e] = rs;
    rankD[e] = rd;
}

// ---------------- fused int2 scan (3 passes) --------------------------------
__global__ __launch_bounds__(256) void k_scan1(const int* __restrict__ cntO,
                                               const int* __restrict__ cntI,
                                               int2* __restrict__ bsum, int n) {
    __shared__ int2 l[256];
    int i = blockIdx.x * 256 + threadIdx.x;
    l[threadIdx.x] = (i < n) ? make_int2(cntO[i], cntI[i]) : make_int2(0, 0);
    __syncthreads();
    for (int s = 128; s > 0; s >>= 1) {
        if (threadIdx.x < s) {
            l[threadIdx.x].x += l[threadIdx.x + s].x;
            l[threadIdx.x].y += l[threadIdx.x + s].y;
        }
        __syncthreads();
    }
    if (threadIdx.x == 0) bsum[blockIdx.x] = l[0];
}
__global__ __launch_bounds__(512) void k_scan2(int2* __restrict__ bsum, int nb,
                                               int* __restrict__ offON,
                                               int* __restrict__ offIN) {
    __shared__ int2 l[512];
    int t = threadIdx.x;
    int2 v = (t < nb) ? bsum[t] : make_int2(0, 0);
    l[t] = v;
    __syncthreads();
    for (int s = 1; s < 512; s <<= 1) {
        int2 tmp = (t >= s) ? l[t - s] : make_int2(0, 0);
        __syncthreads();
        l[t].x += tmp.x; l[t].y += tmp.y;
        __syncthreads();
    }
    if (t < nb) bsum[t] = make_int2(l[t].x - v.x, l[t].y - v.y);
    if (t == 511) { *offON = l[511].x; *offIN = l[511].y; }
}
__global__ __launch_bounds__(256) void k_scan3off(const int* __restrict__ cntO,
                                                  const int* __restrict__ cntI,
                                                  const int2* __restrict__ bsum,
                                                  int* __restrict__ offO,
                                                  int* __restrict__ offI, int n) {
    __shared__ int2 l[256];
    int i = blockIdx.x * 256 + threadIdx.x;
    int2 v = (i < n) ? make_int2(cntO[i], cntI[i]) : make_int2(0, 0);
    l[threadIdx.x] = v;
    __syncthreads();
    for (int s = 1; s < 256; s <<= 1) {
        int2 tmp = (threadIdx.x >= (unsigned)s) ? l[threadIdx.x - s] : make_int2(0, 0);
        __syncthreads();
        l[threadIdx.x].x += tmp.x; l[threadIdx.x].y += tmp.y;
        __syncthreads();
    }
    if (i < n) {
        int2 bs = bsum[blockIdx.x];
        offO[i] = l[threadIdx.x].x - v.x + bs.x;
        offI[i] = l[threadIdx.x].y - v.y + bs.y;
    }
}

// ------- CSR placement: 2 scattered stores/edge, fp8 ef embedded ------------
__global__ __launch_bounds__(256) void k_place(const int* __restrict__ ei,
                                               const int* __restrict__ rankS,
                                               const int* __restrict__ rankD,
                                               const int* __restrict__ offO,
                                               const int* __restrict__ offI,
                                               const uint2* __restrict__ efp,
                                               uint2* __restrict__ out_rec,
                                               uint4* __restrict__ in_rec, int E) {
    int e = blockIdx.x * blockDim.x + threadIdx.x;
    if (e >= E) return;
    int s = ei[e], d = ei[E + e];
    uint2 f = efp[e];
    out_rec[offO[s] + rankS[e]] = f;
    in_rec[offI[d] + rankD[e]] = make_uint4((unsigned)s, f.x, f.y, 0u);
}

// ------- per node: nef sums + dinv + in_src emit + FUSED layer-1 matmul -----
// output: single fp8 table, 64B rows (16 uints; uint c holds cols 4c..4c+3)
__global__ __launch_bounds__(256) void k_nefmm1(
    const int* __restrict__ offO, const uint2* __restrict__ out_rec,
    const int* __restrict__ offI, const uint4* __restrict__ in_rec,
    const float* __restrict__ x, const float* __restrict__ W1,
    float* __restrict__ dinv, int* __restrict__ in_src,
    unsigned* __restrict__ sOut, int n) {
    __shared__ float sW1[384];
    int t = threadIdx.x;
    for (int idx = t; idx < 384; idx += 256) sW1[idx] = W1[idx];
    __syncthreads();

    int i = blockIdx.x * blockDim.x + t;
    if (i >= n) return;
    int bo = offO[i], eo = offO[i + 1];
    int bi = offI[i], eiN = offI[i + 1];
    float a0 = 0.f, a1 = 0.f, a2 = 0.f, a3 = 0.f, a4 = 0.f, a5 = 0.f;
    for (int j = bo; j < eo; ++j) {
        uint2 q = out_rec[j];
        floatx2 p01 = __builtin_amdgcn_cvt_pk_f32_fp8(q.x, false);
        floatx2 p23 = __builtin_amdgcn_cvt_pk_f32_fp8(q.x, true);
        floatx2 p45 = __builtin_amdgcn_cvt_pk_f32_fp8(q.y, false);
        a0 += p01.x; a1 += p01.y; a2 += p23.x;
        a3 += p23.y; a4 += p45.x; a5 += p45.y;
    }
    for (int j = bi; j < eiN; ++j) {
        uint4 r = in_rec[j];
        __builtin_nontemporal_store((int)r.x, in_src + j);   // compact stream
        floatx2 p01 = __builtin_amdgcn_cvt_pk_f32_fp8(r.y, false);
        floatx2 p23 = __builtin_amdgcn_cvt_pk_f32_fp8(r.y, true);
        floatx2 p45 = __builtin_amdgcn_cvt_pk_f32_fp8(r.z, false);
        a0 += p01.x; a1 += p01.y; a2 += p23.x;
        a3 += p23.y; a4 += p45.x; a5 += p45.y;
    }
    int indeg = eiN - bi;
    float degf = (float)((eo - bo) + indeg);
    float inv = 0.5f / fmaxf(degf, 1.f);
    const float2* xr = (const float2*)(x + (size_t)i * 6);
    float2 x01 = xr[0], x23 = xr[1], x45 = xr[2];
    float xp0 = x01.x + a0 * inv, xp1 = x01.y + a1 * inv;
    float xp2 = x23.x + a2 * inv, xp3 = x23.y + a3 * inv;
    float xp4 = x45.x + a4 * inv, xp5 = x45.y + a5 * inv;
    float dv = 1.f / sqrtf(1.f + (float)indeg);
    dinv[i] = dv;

    // layer 1: s1 = fp8(dv * (xp @ W1)) -> 16 packed uints
    unsigned u[16];
#pragma unroll
    for (int c4 = 0; c4 < 16; ++c4) {
        float tv[4];
#pragma unroll
        for (int k = 0; k < 4; ++k) {
            int c = c4 * 4 + k;
            float v = xp0 * sW1[c] + xp1 * sW1[64 + c] + xp2 * sW1[128 + c]
                    + xp3 * sW1[192 + c] + xp4 * sW1[256 + c] + xp5 * sW1[320 + c];
            tv[k] = v * dv;
        }
        u[c4] = pk_fp8x4(tv[0], tv[1], tv[2], tv[3]);
    }
#pragma unroll
    for (int q4 = 0; q4 < 4; ++q4) {
        uint32x4 v = {u[q4 * 4 + 0], u[q4 * 4 + 1], u[q4 * 4 + 2], u[q4 * 4 + 3]};
        __builtin_nontemporal_store(v, (uint32x4*)(sOut + (size_t)i * 16) + q4);
    }
}

// ------- FUSED gather+mm, fp8 rows (64B): 16 lanes x uint per row -----------
__global__ __launch_bounds__(256) void k_gathermm(
    const int* __restrict__ offI, const int* __restrict__ in_src,
    const float* __restrict__ dinv, const unsigned* __restrict__ sIn,
    const float* __restrict__ bias, const float* __restrict__ W,
    unsigned* __restrict__ sOut, int n) {
    int lane = threadIdx.x & 63;
    int sub = lane & 15, grp = lane >> 4;
    int wid = (blockIdx.x * blockDim.x + threadIdx.x) >> 6;
    int nw = (gridDim.x * blockDim.x) >> 6;
    float w[64];
#pragma unroll
    for (int c = 0; c < 64; ++c) w[c] = W[c * 64 + lane];
    float4 bb = ((const float4*)bias)[sub];

    for (int i = wid; i < n; i += nw) {
        unsigned su = sIn[(size_t)i * 16 + sub];
        float a0, a1, a2, a3;
        if (grp == 0) {
            floatx2 lo = __builtin_amdgcn_cvt_pk_f32_fp8(su, false);
            floatx2 hi = __builtin_amdgcn_cvt_pk_f32_fp8(su, true);
            a0 = lo.x; a1 = lo.y; a2 = hi.x; a3 = hi.y;
        } else { a0 = a1 = a2 = a3 = 0.f; }
        int b0 = offI[i], e0 = offI[i + 1];
#pragma unroll 4
        for (int j = b0 + grp; j < e0; j += 4) {
            unsigned src = (unsigned)__builtin_nontemporal_load(in_src + j);
            unsigned u = sIn[(size_t)src * 16 + sub];
            floatx2 lo = __builtin_amdgcn_cvt_pk_f32_fp8(u, false);
            floatx2 hi = __builtin_amdgcn_cvt_pk_f32_fp8(u, true);
            a0 += lo.x; a1 += lo.y; a2 += hi.x; a3 += hi.y;
        }
        a0 += __shfl_xor(a0, 16); a1 += __shfl_xor(a1, 16);
        a2 += __shfl_xor(a2, 16); a3 += __shfl_xor(a3, 16);
        a0 += __shfl_xor(a0, 32); a1 += __shfl_xor(a1, 32);
        a2 += __shfl_xor(a2, 32); a3 += __shfl_xor(a3, 32);

        float dv = dinv[i];
        float h0 = fmaxf(fmaf(a0, dv, bb.x), 0.f);
        float h1 = fmaxf(fmaf(a1, dv, bb.y), 0.f);
        float h2 = fmaxf(fmaf(a2, dv, bb.z), 0.f);
        float h3 = fmaxf(fmaf(a3, dv, bb.w), 0.f);
        float o = 0.f;
#pragma unroll
        for (int g = 0; g < 16; ++g) {
            o = fmaf(rdlane(h0, g), w[g * 4 + 0], o);
            o = fmaf(rdlane(h1, g), w[g * 4 + 1], o);
            o = fmaf(rdlane(h2, g), w[g * 4 + 2], o);
            o = fmaf(rdlane(h3, g), w[g * 4 + 3], o);
        }
        o *= dv;
        float o0 = __shfl(o, sub * 4 + 0);
        float o1 = __shfl(o, sub * 4 + 1);
        float o2 = __shfl(o, sub * 4 + 2);
        float o3 = __shfl(o, sub * 4 + 3);
        if (lane < 16)
            __builtin_nontemporal_store(pk_fp8x4(o0, o1, o2, o3),
                                        sOut + (size_t)i * 16 + lane);
    }
}

// ------- FUSED final gather + b3 + pooled sum/sumsq, fp8 rows ---------------
__global__ __launch_bounds__(256) void k_gatherreduce(
    const int* __restrict__ offI, const int* __restrict__ in_src,
    const float* __restrict__ dinv, const unsigned* __restrict__ sIn,
    const float* __restrict__ b3, double* __restrict__ sums, int n) {
    int lane = threadIdx.x & 63;
    int sub = lane & 15, grp = lane >> 4;
    int wv = threadIdx.x >> 6;
    int wid = (blockIdx.x * blockDim.x + threadIdx.x) >> 6;
    int nw = (gridDim.x * blockDim.x) >> 6;
    float4 bb = ((const float4*)b3)[sub];
    double s0 = 0.0, s1 = 0.0, s2_ = 0.0, s3 = 0.0;
    double q0 = 0.0, q1 = 0.0, q2 = 0.0, q3 = 0.0;

    for (int i = wid; i < n; i += nw) {
        unsigned su = sIn[(size_t)i * 16 + sub];
        float a0, a1, a2, a3;
        if (grp == 0) {
            floatx2 lo = __builtin_amdgcn_cvt_pk_f32_fp8(su, false);
            floatx2 hi = __builtin_amdgcn_cvt_pk_f32_fp8(su, true);
            a0 = lo.x; a1 = lo.y; a2 = hi.x; a3 = hi.y;
        } else { a0 = a1 = a2 = a3 = 0.f; }
        int b0 = offI[i], e0 = offI[i + 1];
#pragma unroll 4
        for (int j = b0 + grp; j < e0; j += 4) {
            unsigned src = (unsigned)__builtin_nontemporal_load(in_src + j);
            unsigned u = sIn[(size_t)src * 16 + sub];
            floatx2 lo = __builtin_amdgcn_cvt_pk_f32_fp8(u, false);
            floatx2 hi = __builtin_amdgcn_cvt_pk_f32_fp8(u, true);
            a0 += lo.x; a1 += lo.y; a2 += hi.x; a3 += hi.y;
        }
        a0 += __shfl_xor(a0, 16); a1 += __shfl_xor(a1, 16);
        a2 += __shfl_xor(a2, 16); a3 += __shfl_xor(a3, 16);
        a0 += __shfl_xor(a0, 32); a1 += __shfl_xor(a1, 32);
        a2 += __shfl_xor(a2, 32); a3 += __shfl_xor(a3, 32);

        float dv = dinv[i];
        float v0 = fmaf(a0, dv, bb.x);
        float v1 = fmaf(a1, dv, bb.y);
        float v2 = fmaf(a2, dv, bb.z);
        float v3 = fmaf(a3, dv, bb.w);
        s0 += v0; s1 += v1; s2_ += v2; s3 += v3;
        q0 += (double)v0 * v0; q1 += (double)v1 * v1;
        q2 += (double)v2 * v2; q3 += (double)v3 * v3;
    }
    __shared__ double shS[4 * 64], shQ[4 * 64];
    if (grp == 0) {
#pragma unroll
        for (int k = 0; k < 4; ++k) {
            double sk = (k == 0) ? s0 : (k == 1) ? s1 : (k == 2) ? s2_ : s3;
            double qk = (k == 0) ? q0 : (k == 1) ? q1 : (k == 2) ? q2 : q3;
            shS[wv * 64 + sub * 4 + k] = sk;
            shQ[wv * 64 + sub * 4 + k] = qk;
        }
    }
    __syncthreads();
    if (wv == 0) {
        double a = shS[lane] + shS[64 + lane] + shS[128 + lane] + shS[192 + lane];
        double c = shQ[lane] + shQ[64 + lane] + shQ[128 + lane] + shQ[192 + lane];
        unsafeAtomicAdd(&sums[lane], a);
        unsafeAtomicAdd(&sums[64 + lane], c);
    }
}

// ---------------- head MLP + sigmoid (single block) -------------------------
__global__ void k_head(const double* __restrict__ sums,
                       const float* __restrict__ Wp1, const float* __restrict__ bp1,
                       const float* __restrict__ Wp2, const float* __restrict__ bp2,
                       const float* __restrict__ Wp3, const float* __restrict__ bp3,
                       float* __restrict__ out, int n) {
    __shared__ float comb[192], p1[64], p2[32];
    int t = threadIdx.x;
    if (t < 64) {
        double s = sums[t], s2 = sums[64 + t];
        double m = s / n;
        double var = (s2 - s * s / n) / (double)(n - 1);
        float mf = (float)m;
        float sd = (float)sqrt(var > 0.0 ? var : 0.0);
        comb[t] = mf;
        comb[64 + t] = mf;
        comb[128 + t] = sd;
    }
    __syncthreads();
    if (t < 64) {
        float acc = bp1[t];
        for (int k = 0; k < 192; ++k) acc = fmaf(comb[k], Wp1[k * 64 + t], acc);
        p1[t] = fmaxf(acc, 0.f);
    }
    __syncthreads();
    if (t < 32) {
        float acc = bp2[t];
        for (int k = 0; k < 64; ++k) acc = fmaf(p1[k], Wp2[k * 32 + t], acc);
        p2[t] = fmaxf(acc, 0.f);
    }
    __syncthreads();
    if (t == 0) {
        float acc = bp3[0];
        for (int k = 0; k < 32; ++k) acc = fmaf(p2[k], Wp3[k], acc);
        out[0] = 1.f / (1.f + expf(-acc));
    }
}

static inline char* align16(char* p) {
    return (char*)(((uintptr_t)p + 15) & ~(uintptr_t)15);
}

extern "C" void kernel_launch(void* const* d_in, const int* in_sizes, int n_in,
                              void* d_out, int out_size, void* d_ws, size_t ws_size,
                              hipStream_t stream) {
    const float* x   = (const float*)d_in[0];
    const int*   ei  = (const int*)d_in[1];
    const float* ea  = (const float*)d_in[2];
    const float* W1  = (const float*)d_in[3];
    const float* b1  = (const float*)d_in[4];
    const float* W2  = (const float*)d_in[5];
    const float* b2  = (const float*)d_in[6];
    const float* W3  = (const float*)d_in[7];
    const float* b3  = (const float*)d_in[8];
    const float* We1 = (const float*)d_in[9];
    const float* be1 = (const float*)d_in[10];
    const float* We2 = (const float*)d_in[11];
    const float* be2 = (const float*)d_in[12];
    const float* Wp1 = (const float*)d_in[13];
    const float* bp1 = (const float*)d_in[14];
    const float* Wp2 = (const float*)d_in[15];
    const float* bp2 = (const float*)d_in[16];
    const float* Wp3 = (const float*)d_in[17];
    const float* bp3 = (const float*)d_in[18];

    const int N = in_sizes[0] / 6;
    const int E = in_sizes[1] / 2;
    const int nbN = (N + 255) / 256;
    const int nbE = (E + 255) / 256;
    const size_t SB = ((size_t)N * 64 + 15) & ~(size_t)15;  // fp8 table 6.4MB (== E*4)

    // ---- workspace layout (~72 MB) ----
    char* p = (char*)d_ws;
    double* sums = (double*)p;          p = align16(p + 128 * sizeof(double));
    int* cntO = (int*)p;                p = align16(p + (size_t)N * 4);
    int* cntI = (int*)p;                p = align16(p + (size_t)N * 4);
    int* offO = (int*)p;                p = align16(p + ((size_t)N + 1) * 4);
    int* offI = (int*)p;                p = align16(p + ((size_t)N + 1) * 4);
    int2* bsum = (int2*)p;              p = align16(p + 512 * 8);
    float* dinv = (float*)p;            p = align16(p + (size_t)N * 4);
    int* in_src = (int*)p;              p = align16(p + (size_t)E * 4);
    uint4* in_rec = (uint4*)p;          p = align16(p + (size_t)E * 16);
    // U1: rankS/rankD (E*4 each) die after k_place -> sbufA/sbufB fp8 tables
    char* u1 = p;                       p = align16(p + 2 * SB);
    int* rankS = (int*)u1;
    int* rankD = (int*)(u1 + SB);
    unsigned* sbufA = (unsigned*)u1;
    unsigned* sbufB = (unsigned*)(u1 + SB);
    // U2: efp (E*8) + out_rec (E*8) die after k_nefmm1
    char* u2 = p;
    uint2* efp = (uint2*)u2;
    uint2* out_rec = (uint2*)(u2 + (size_t)E * 8);

    dim3 blk(256);

    k_zero<<<dim3(nbN), blk, 0, stream>>>(cntO, cntI, sums, N);
    k_front<<<dim3(nbE), blk, 0, stream>>>(ei, ea, We1, be1, We2, be2,
                                           efp, cntO, cntI, rankS, rankD, E);
    k_scan1<<<dim3(nbN), blk, 0, stream>>>(cntO, cntI, bsum, N);
    k_scan2<<<dim3(1), dim3(512), 0, stream>>>(bsum, nbN, offO + N, offI + N);
    k_scan3off<<<dim3(nbN), blk, 0, stream>>>(cntO, cntI, bsum, offO, offI, N);
    k_place<<<dim3(nbE), blk, 0, stream>>>(ei, rankS, rankD, offO, offI, efp,
                                           out_rec, in_rec, E);
    k_nefmm1<<<dim3(nbN), blk, 0, stream>>>(offO, out_rec, offI, in_rec, x, W1,
                                            dinv, in_src, sbufA, N);

    // layers 2,3 fused gather+mm; final fused gather+reduce
    k_gathermm<<<dim3(2048), blk, 0, stream>>>(offI, in_src, dinv, sbufA, b1, W2, sbufB, N);
    k_gathermm<<<dim3(2048), blk, 0, stream>>>(offI, in_src, dinv, sbufB, b2, W3, sbufA, N);
    k_gatherreduce<<<dim3(2048), blk, 0, stream>>>(offI, in_src, dinv, sbufA, b3, sums, N);
    k_head<<<dim3(1), dim3(64), 0, stream>>>(sums, Wp1, bp1, Wp2, bp2, Wp3, bp3,
                                             (float*)d_out, N);
}